// Round 1
// 254.122 us; speedup vs baseline: 1.0000x; 1.0000x over previous
//
#include <hip/hip_runtime.h>

// Problem constants
#define BINS   32
#define NB     64          // batch
#define NCH    3           // channels (merged into one histogram per reference)
#define HH     512
#define WW     512
#define SLICES 8           // blocks per (image, quadrant)

// Native clang vector type: __builtin_nontemporal_load requires a real vector,
// not HIP's float4 struct.
typedef float vfloat4 __attribute__((ext_vector_type(4)));

// ws layout: unsigned scounts[NB][4][SLICES][BINS]  (2048 * 32 u32 = 256 KiB).
// Each block owns one [BINS] slot -> plain stores, no memset, no global atomics.

// Bank-transposed, u16-packed per-wave histograms.
//   whist[wave][bin][pair]: lane l uses column pair = (l>>1)&31, half = l&1.
//   LDS bank of EVERY access = pair (word index = wave*1024 + bin*32 + pair,
//   bank = pair) -> fixed 2-way bank aliasing independent of the random bin,
//   vs. the old layout where bank = bin gave ~6-way random conflicts plus
//   same-address atomic serialization on the shared per-CU LDS unit.
// 16 KiB/block * 8 blocks/CU = 128 KiB <= 160 KiB -> occupancy unchanged.
__global__ __launch_bounds__(256, 8) void hist_main(const float* __restrict__ in,
                                                    unsigned* __restrict__ scounts) {
    __shared__ unsigned whist[4][BINS][32];

    const int t    = threadIdx.x;
    const int bid  = blockIdx.x;
    const int s    = bid & (SLICES - 1);
    const int quad = (bid >> 3) & 3;
    const int b    = bid >> 5;
    const int qr   = quad >> 1;
    const int qc   = quad & 1;

    // zero 4096 words: 16 per thread, stride-256 -> bank = t%32, conflict-free
    #pragma unroll
    for (int k = 0; k < 16; ++k) ((unsigned*)whist)[k * 256 + t] = 0;
    __syncthreads();

    const unsigned inc = 1u << ((t & 1) << 4);          // lo/hi u16 half
    unsigned* const hp = &whist[t >> 6][0][(t >> 1) & 31];

    // Quadrant base (floats): image + quadrant-row-block + quadrant-col-block
    const size_t base = (size_t)b * (NCH * HH * WW)
                      + (size_t)qr * (256 * WW)
                      + (size_t)qc * 256;

    // Each (b,quad) covers 3 channels x 256 rows = 768 "rows" of 256 floats.
    // Slice s handles rows [s*96, (s+1)*96): 96 rows * 64 float4 = 6144 float4,
    // 24 iterations of 256 threads. Lanes 0..63 cover one contiguous 1 KiB row
    // segment -> perfectly coalesced.
    #pragma unroll 2
    for (int it = 0; it < 24; ++it) {
        const int f    = it * 256 + t;      // [0, 6144)
        const int Rrel = f >> 6;            // [0, 96)
        const int col4 = f & 63;            // [0, 64)
        const int R    = s * 96 + Rrel;     // [0, 768)
        const int c    = R >> 8;            // channel
        const int r    = R & 255;           // row within quadrant
        const vfloat4* p = (const vfloat4*)(in + base
                                            + (size_t)c * (HH * WW)
                                            + (size_t)r * WW
                                            + (size_t)col4 * 4);
        const vfloat4 v = __builtin_nontemporal_load(p);   // streaming, read-once
        #pragma unroll
        for (int u = 0; u < 4; ++u) {
            // Input is uniform [0,1): every value valid, bin = floor(32x).
            // Clamp kept so x==1.0 (last bin) would still be exact.
            int bin = (int)(v[u] * 32.0f);
            bin = bin < 0 ? 0 : (bin > 31 ? 31 : bin);
            // ds_add_u32 fire-and-forget; bank = pair, 2-way max.
            atomicAdd(hp + (bin << 5), inc);
        }
    }
    __syncthreads();

    // Reduce 4 waves x 32 pairs x 2 halves per bin.
    // Thread t handles (bin = t>>3, src = t&7): wave w = src&3, half-range hf.
    // All 8 threads of a bin sit in ONE wave -> shfl reduce, then one store.
    {
        const int bin = t >> 3;
        const int src = t & 7;
        const int w   = src & 3;
        const int hf  = src >> 2;
        unsigned part = 0;
        #pragma unroll
        for (int i = 0; i < 16; ++i) {
            // rotate start by bin so concurrent lanes spread across banks
            const int p = hf * 16 + ((i + bin) & 15);
            const unsigned word = whist[w][bin][p];
            part += (word & 0xffffu) + (word >> 16);
        }
        part += __shfl_xor(part, 1);
        part += __shfl_xor(part, 2);
        part += __shfl_xor(part, 4);
        if (src == 0)
            scounts[(((b * 4 + quad) * SLICES) + s) * BINS + bin] = part;
    }
}

// out[b][ch][i][j], ch in [0,96): 0-31 = s0 (global hist), 32-63 = s1 (quadrant),
// 64-95 = zeros (must be written: d_out is poisoned before every launch).
__global__ __launch_bounds__(256) void finalize(const unsigned* __restrict__ scounts,
                                                float* __restrict__ out, int n) {
    const int idx = blockIdx.x * 256 + threadIdx.x;
    if (idx >= n) return;
    const int j  = idx & 3;
    const int i  = (idx >> 2) & 3;
    const int ch = (idx >> 4) % 96;
    const int b  = idx / 1536;           // 96*16
    float val = 0.0f;
    if (ch < 32) {
        unsigned ssum = 0;
        #pragma unroll
        for (int q = 0; q < 4; ++q)
            #pragma unroll
            for (int sl = 0; sl < SLICES; ++sl)
                ssum += scounts[(((b * 4 + q) * SLICES) + sl) * BINS + ch];
        val = (float)ssum * (1.0f / 262144.0f);   // / (h*w), exact pow2
    } else if (ch < 64) {
        const int bin = ch - 32;
        const int q   = (i >> 1) * 2 + (j >> 1);
        unsigned ssum = 0;
        #pragma unroll
        for (int sl = 0; sl < SLICES; ++sl)
            ssum += scounts[(((b * 4 + q) * SLICES) + sl) * BINS + bin];
        val = (float)ssum * (1.0f / 65536.0f);    // / (hh*ww)
    }
    out[idx] = val;
}

extern "C" void kernel_launch(void* const* d_in, const int* in_sizes, int n_in,
                              void* d_out, int out_size, void* d_ws, size_t ws_size,
                              hipStream_t stream) {
    const float* in = (const float*)d_in[0];
    float* out      = (float*)d_out;
    unsigned* scounts = (unsigned*)d_ws;   // NB*4*SLICES*BINS = 64K uints = 256 KiB

    hist_main<<<NB * 4 * SLICES, 256, 0, stream>>>(in, scounts);
    finalize<<<(out_size + 255) / 256, 256, 0, stream>>>(scounts, out, out_size);
}